// Round 2
// baseline (3434.792 us; speedup 1.0000x reference)
//
#include <hip/hip_runtime.h>
#include <hip/hip_bf16.h>

// Problem constants: B=2, T=12 (L), C=128, H=W=32, heads=4, dh=32, layers=5
// All tensors fp32 (reference is jnp.float32 throughout).
// Activations: (B*L=24, 128, 32, 32) fp32 = 3,145,728 floats per buffer.
#define NELEM 3145728
#define IMG 24          // B*L
#define CH 128
#define HW 1024         // 32*32

// ---------------- 3x3 SAME conv ----------------
// Block: one image (blockIdx.x in 0..23), 16 out channels (blockIdx.y*16),
// 8 output rows (blockIdx.z*8). 256 threads = 8 rows x 32 cols, 16 acc/thread.
// CIN = input channels per group (32 -> grouped/head-block-diagonal, 128 -> dense).
// Weights are read with wave-uniform indices directly from global -> s_load +
// v_fmac with SGPR operand (keeps vector-issue slots for FMAs).
template<int CIN, bool RELU, bool RES>
__global__ __launch_bounds__(256) void k_conv3x3(
    const float* __restrict__ x, const float* __restrict__ w,
    const float* __restrict__ bias, const float* __restrict__ res,
    float* __restrict__ out)
{
    const int bl = blockIdx.x;
    const int co_base = blockIdx.y * 16;
    const int y0 = blockIdx.z * 8;
    const int t = threadIdx.x;
    const int r = t >> 5, xx = t & 31;
    const int cin_base = (CIN == 32) ? (co_base & ~31) : 0;  // head*32 when grouped

    __shared__ float sx[8 * 10 * 34];   // 8 ch x 10 rows x 34 cols = 2720

    float acc[16];
    #pragma unroll
    for (int i = 0; i < 16; i++) acc[i] = 0.f;

    const float* xb = x + bl * CH * HW;

    for (int ch = 0; ch < CIN / 8; ch++) {
        const int ci0 = ch * 8;
        // stage input tile (zero-padded borders)
        for (int idx = t; idx < 2720; idx += 256) {
            int ci = idx / 340; int rem = idx - ci * 340;
            int row = rem / 34; int col = rem - row * 34;
            int gy = y0 - 1 + row, gx = col - 1;
            float val = 0.f;
            if (gy >= 0 && gy < 32 && gx >= 0 && gx < 32)
                val = xb[(cin_base + ci0 + ci) * HW + gy * 32 + gx];
            sx[idx] = val;
        }
        __syncthreads();
        // weights for this chunk: w[(co*CIN + ci)*9 + tap], uniform indices
        const float* wb = w + (co_base * CIN + ci0) * 9;
        #pragma unroll
        for (int ci = 0; ci < 8; ci++) {
            #pragma unroll
            for (int ky = 0; ky < 3; ky++) {
                #pragma unroll
                for (int kx = 0; kx < 3; kx++) {
                    float xv = sx[ci * 340 + (r + ky) * 34 + xx + kx];
                    #pragma unroll
                    for (int co = 0; co < 16; co++)
                        acc[co] = fmaf(xv, wb[co * CIN * 9 + ci * 9 + ky * 3 + kx], acc[co]);
                }
            }
        }
        __syncthreads();
    }

    const int yy = y0 + r;
    const int obase = bl * CH * HW + yy * 32 + xx;
    #pragma unroll
    for (int co = 0; co < 16; co++) {
        float val = acc[co] + bias[co_base + co];
        if (RELU) val = fmaxf(val, 0.f);
        int oi = obase + (co_base + co) * HW;
        if (RES) val += res[oi];
        out[oi] = val;
    }
}

// ---------------- attention logit conv: Ak = conv3x3(v + pos, aw_k) ----------------
// Only the K half of att_w matters: att[b,lq,lk] = f(q[lq]) + g(k[lk]) + ab and
// softmax over lk cancels the lq-dependent part and ab entirely.
// Block: (image bl, head h, 8-row slab). Output ak[((b*4+h)*12 + l)*1024 + yx].
__global__ __launch_bounds__(256) void k_attn(
    const float* __restrict__ v, const float* __restrict__ aw,
    float* __restrict__ ak)
{
    const int bl = blockIdx.x;
    const int h = blockIdx.y;
    const int y0 = blockIdx.z * 8;
    const int t = threadIdx.x;
    const int r = t >> 5, xx = t & 31;
    const int b = bl / 12, l = bl - b * 12;

    __shared__ float sx[2720];
    __shared__ float spos[32];

    if (t < 32) {
        int j2 = t & ~1;
        float freq = expf(-(float)j2 * 0.28782313662425576f);  // ln(10000)/32
        float ang = (float)l * freq;
        spos[t] = (t & 1) ? cosf(ang) : sinf(ang);
    }
    __syncthreads();

    // K-half weights: aw[(h*64 + 32 + ci)*9 + tap], uniform indices
    const float* wb = aw + (h * 64 + 32) * 9;

    float acc = 0.f;
    for (int ch = 0; ch < 4; ch++) {
        const int ci0 = ch * 8;
        for (int idx = t; idx < 2720; idx += 256) {
            int ci = idx / 340; int rem = idx - ci * 340;
            int row = rem / 34; int col = rem - row * 34;
            int gy = y0 - 1 + row, gx = col - 1;
            float val = 0.f;
            if (gy >= 0 && gy < 32 && gx >= 0 && gx < 32)
                val = v[(bl * CH + h * 32 + ci0 + ci) * HW + gy * 32 + gx] + spos[ci0 + ci];
            sx[idx] = val;
        }
        __syncthreads();
        #pragma unroll
        for (int ci = 0; ci < 8; ci++)
            #pragma unroll
            for (int ky = 0; ky < 3; ky++)
                #pragma unroll
                for (int kx = 0; kx < 3; kx++)
                    acc = fmaf(sx[ci * 340 + (r + ky) * 34 + xx + kx],
                               wb[(ci0 + ci) * 9 + ky * 3 + kx], acc);
        __syncthreads();
    }
    ak[((b * 4 + h) * 12 + l) * HW + (y0 + r) * 32 + xx] = acc;
}

// ---------------- softmax over the 12 key frames (in-place) ----------------
__global__ void k_softmax(float* __restrict__ akw){
    int gid = blockIdx.x * blockDim.x + threadIdx.x;   // 8192 = B*4heads*1024
    if (gid >= 8192) return;
    int b = gid >> 12, rem = gid & 4095, h = rem >> 10, yx = rem & 1023;
    float* p = akw + ((b * 4 + h) * 12) * HW + yx;
    float a[12], m = -1e30f;
    #pragma unroll
    for (int l = 0; l < 12; l++) { a[l] = p[l * HW]; m = fmaxf(m, a[l]); }
    float s = 0.f;
    #pragma unroll
    for (int l = 0; l < 12; l++) { a[l] = expf(a[l] - m); s += a[l]; }
    float inv = 1.f / s;
    #pragma unroll
    for (int l = 0; l < 12; l++) p[l * HW] = a[l] * inv;
}

// ---------------- weighted sum over key frames + residual (in-place on cur) ----------------
// Softmax weights are lq-independent -> head output identical for all 12 query
// frames: compute s once, add to all 12 frames.
__global__ void k_wsum(const float* __restrict__ akw, const float* __restrict__ v,
                       float* __restrict__ cur){
    int gid = blockIdx.x * blockDim.x + threadIdx.x;   // 262144 = B*128*1024
    int b = gid >> 17, rem = gid & 131071, c = rem >> 10, yx = rem & 1023;
    int h = c >> 5;
    const float* wp = akw + ((b * 4 + h) * 12) * HW + yx;
    const float* vp = v + (b * 12 * CH + c) * HW + yx;
    float s = 0.f;
    #pragma unroll
    for (int l = 0; l < 12; l++) s += wp[l * HW] * vp[l * CH * HW];
    float* cp = cur + (b * 12 * CH + c) * HW + yx;
    #pragma unroll
    for (int l = 0; l < 12; l++) cp[l * CH * HW] += s;
}

// ---------------- GroupNorm (groups=4, 32 ch x 1024 spatial per group) ----------------
__global__ __launch_bounds__(256) void k_gn(const float* __restrict__ xin,
    const float* __restrict__ gw, const float* __restrict__ gb,
    float* __restrict__ out)
{
    const int bl = blockIdx.x, g = blockIdx.y;
    const int t = threadIdx.x;
    const float* xp = xin + (bl * CH + g * 32) * HW;
    float s = 0.f, s2 = 0.f;
    for (int i = t; i < 32768; i += 256) { float val = xp[i]; s += val; s2 += val * val; }
    __shared__ float rs[256], rs2[256];
    rs[t] = s; rs2[t] = s2; __syncthreads();
    for (int ofs = 128; ofs > 0; ofs >>= 1) {
        if (t < ofs) { rs[t] += rs[t + ofs]; rs2[t] += rs2[t + ofs]; }
        __syncthreads();
    }
    const float mu = rs[0] * (1.f / 32768.f);
    const float var = rs2[0] * (1.f / 32768.f) - mu * mu;
    const float inv = rsqrtf(var + 1e-5f);
    const int obase = (bl * CH + g * 32) * HW;
    for (int i = t; i < 32768; i += 256) {
        int c = i >> 10; int gc = g * 32 + c;
        out[obase + i] = (xp[i] - mu) * inv * gw[gc] + gb[gc];
    }
}

extern "C" void kernel_launch(void* const* d_in, const int* in_sizes, int n_in,
                              void* d_out, int out_size, void* d_ws, size_t ws_size,
                              hipStream_t stream)
{
    const float* input = (const float*)d_in[0];
    // d_in[1] (q_w), d_in[2] (q_b), d_in[6] (att_b) are provably unused:
    // softmax over the key axis cancels all query-dependent logit terms.
    const float* kv_w  = (const float*)d_in[3];
    const float* kv_b  = (const float*)d_in[4];
    const float* att_w = (const float*)d_in[5];
    const float* ff1_w = (const float*)d_in[7];
    const float* ff1_b = (const float*)d_in[8];
    const float* ff2_w = (const float*)d_in[9];
    const float* ff2_b = (const float*)d_in[10];
    const float* gn_w  = (const float*)d_in[11];
    const float* gn_b  = (const float*)d_in[12];

    float* ws  = (float*)d_ws;
    float* cur = ws;                     // current activations (B,L,C,H,W)
    float* v   = ws + (size_t)NELEM;     // v tensor; reused as ff2 output
    float* akw = ws + (size_t)2 * NELEM; // attn logits -> softmax weights (B,4,12,1024)
    float* f1  = (float*)d_out;          // relu(ff1) scratch; overwritten by final GN
    float* outp = (float*)d_out;

    // cur = input (fp32 copy)
    hipMemcpyAsync(cur, input, (size_t)NELEM * sizeof(float),
                   hipMemcpyDeviceToDevice, stream);

    for (int li = 0; li < 5; li++) {
        // v = grouped conv(cur, kv_w) + kv_b   (head-block-diagonal 128->128)
        k_conv3x3<32, false, false><<<dim3(IMG, 8, 4), 256, 0, stream>>>(
            cur, kv_w + (size_t)li * 36864, kv_b + li * 128, nullptr, v);
        // attention logits from k = v + pos  (only K-half of att_w matters)
        k_attn<<<dim3(IMG, 4, 4), 256, 0, stream>>>(v, att_w + (size_t)li * 2304, akw);
        // softmax over key frames
        k_softmax<<<32, 256, 0, stream>>>(akw);
        // cur += sum_l w*v  (attention output + residual, broadcast over query frames)
        k_wsum<<<1024, 256, 0, stream>>>(akw, v, cur);
        // f1 = relu(conv(cur, ff1_w) + ff1_b)
        k_conv3x3<128, true, false><<<dim3(IMG, 8, 4), 256, 0, stream>>>(
            cur, ff1_w + (size_t)li * 147456, ff1_b + li * 128, nullptr, f1);
        // v = conv(f1, ff2_w) + ff2_b + cur   (ff output + residual)
        k_conv3x3<128, false, true><<<dim3(IMG, 8, 4), 256, 0, stream>>>(
            f1, ff2_w + (size_t)li * 147456, ff2_b + li * 128, cur, v);
        // group norm -> cur (layers 0-3) or d_out (last layer)
        k_gn<<<dim3(IMG, 4), 256, 0, stream>>>(
            v, gn_w + li * 128, gn_b + li * 128, (li == 4) ? outp : cur);
    }
}

// Round 3
// 858.841 us; speedup vs baseline: 3.9993x; 3.9993x over previous
//
#include <hip/hip_runtime.h>

// Problem: B=2, T=12, C=128, H=W=32, heads=4, dh=32, layers=5. All fp32 I/O.
// Key algebra: softmax over the key axis cancels the q-conv and att_b entirely,
// and makes the attention weights query-independent (head output identical for
// all 12 frames). Dense/grouped 3x3 convs -> implicit GEMM on bf16 MFMA.
#define NELEM 3145728   // 24*128*1024
#define IMG 24
#define CH 128
#define HW 1024

using short8  = __attribute__((ext_vector_type(8))) short;
using float4v = __attribute__((ext_vector_type(4))) float;

__device__ inline unsigned short f2bf(float f){
    union { float f; unsigned u; } c; c.f = f;
    return (unsigned short)((c.u + 0x7FFF + ((c.u >> 16) & 1)) >> 16);
}

// ---------------- weight transforms (fp32 -> bf16 MFMA-B layout) ----------------
// Dense: W2[li2][tap][cc][quad][co][j] = w[co][ci=cc*32+quad*8+j][tap], li2 = li*2+s
__global__ void k_w2dense(const float* __restrict__ w1, const float* __restrict__ w2src,
                          unsigned short* __restrict__ dst){
    int idx = blockIdx.x * 256 + threadIdx.x;           // 10*147456
    if (idx >= 1474560) return;
    int li2 = idx / 147456, r1 = idx - li2 * 147456;
    int j = r1 & 7, t16 = r1 >> 3;
    int co = t16 & 127, tcq = t16 >> 7;
    int quad = tcq & 3, cc = (tcq >> 2) & 3, tap = tcq >> 4;
    const float* base = ((li2 & 1) ? w2src : w1) + (size_t)(li2 >> 1) * 147456;
    dst[idx] = f2bf(base[(co * 128 + cc * 32 + quad * 8 + j) * 9 + tap]);
}
// Grouped kv: W2[li][tap][quad][co(=h*32+col)][j] = kv_w[li][h][col][ci=quad*8+j][tap]
__global__ void k_w2kv(const float* __restrict__ w, unsigned short* __restrict__ dst){
    int idx = blockIdx.x * 256 + threadIdx.x;           // 5*36864
    if (idx >= 184320) return;
    int li = idx / 36864, r1 = idx - li * 36864;
    int j = r1 & 7, t16 = r1 >> 3;
    int co = t16 & 127, tq = t16 >> 7;
    int quad = tq & 3, tap = tq >> 2;
    int h = co >> 5, col = co & 31;
    dst[idx] = f2bf(w[(size_t)(((li * 4 + h) * 32 + col) * 32 + quad * 8 + j) * 9 + tap]);
}

// ---------------- implicit-GEMM 3x3 conv via bf16 MFMA ----------------
// Block: 128 px (4 image rows) x 128 co; 2x2 waves, each 4x4 tiles of 16x16.
// A (input) in LDS: [oct(16)][pos(204 pad 205)][8ci] bf16; staged once.
// B (weights) read from global W2 (L2-resident, frag-native layout).
template<bool GROUPED, bool RELU, bool RES>
__global__ __launch_bounds__(256) void k_conv_mfma(
    const float* __restrict__ x, const unsigned short* __restrict__ w2,
    const float* __restrict__ bias, const float* __restrict__ res,
    float* __restrict__ out)
{
    const int rq = blockIdx.x;       // 0..7 -> y0 = rq*4
    const int bl = blockIdx.y;       // 0..23
    const int y0 = rq * 4;
    const int t = threadIdx.x;
    const int wave = t >> 6, lane = t & 63;
    const int wave_m = wave & 1, wave_n = wave >> 1;
    const int n16 = lane & 15, quad = lane >> 4;

    __shared__ short8 sA[16 * 205];   // 52480 B

    // ---- stage A: rows y0-1..y0+4 (6) x cols -1..32 (34) x 128 ci, bf16 ----
    for (int idx = t; idx < 16 * 204; idx += 256) {
        int oct = idx / 204, pos = idx - oct * 204;
        int row = pos / 34, col = pos - row * 34;
        int gy = y0 - 1 + row, gx = col - 1;
        bool ok = (gy >= 0 && gy < 32 && gx >= 0 && gx < 32);
        const float* gp = x + ((size_t)bl * CH + oct * 8) * HW + gy * 32 + gx;
        short8 v;
        #pragma unroll
        for (int j = 0; j < 8; j++)
            v[j] = (short)f2bf(ok ? gp[j * HW] : 0.f);
        sA[oct * 205 + pos] = v;
    }
    __syncthreads();

    float4v acc[4][4];
    #pragma unroll
    for (int a = 0; a < 4; a++)
        #pragma unroll
        for (int b = 0; b < 4; b++) acc[a][b] = (float4v){0.f, 0.f, 0.f, 0.f};

    const short8* w8 = reinterpret_cast<const short8*>(w2);

    for (int tap = 0; tap < 9; tap++) {
        const int ky = tap / 3, kx = tap - ky * 3;
        #pragma unroll
        for (int cc = 0; cc < 4; cc++) {
            // A fragments: Mt 0..3 (wave covers 64 px)
            short8 af[4];
            #pragma unroll
            for (int mt = 0; mt < 4; mt++) {
                int m128 = wave_m * 64 + mt * 16;
                int r = m128 >> 5, xh = m128 & 31;
                int pos = (r + ky) * 34 + xh + n16 + kx;
                af[mt] = sA[(cc * 4 + quad) * 205 + pos];
            }
            if (!GROUPED) {
                short8 bf[4];
                #pragma unroll
                for (int nt = 0; nt < 4; nt++) {
                    int co = wave_n * 64 + nt * 16 + n16;
                    bf[nt] = w8[(((tap * 4 + cc) * 4 + quad) * 128) + co];
                }
                #pragma unroll
                for (int mt = 0; mt < 4; mt++)
                    #pragma unroll
                    for (int nt = 0; nt < 4; nt++)
                        acc[mt][nt] = __builtin_amdgcn_mfma_f32_16x16x32_bf16(
                            af[mt], bf[nt], acc[mt][nt], 0, 0, 0);
            } else {
                // block-diagonal: co-head must equal cc (ci chunk)
                int hs = cc - wave_n * 2;          // wave covers heads 2wn, 2wn+1
                if (hs >= 0 && hs < 2) {
                    #pragma unroll
                    for (int n2 = 0; n2 < 2; n2++) {
                        int nt = hs * 2 + n2;
                        int co = wave_n * 64 + nt * 16 + n16;
                        short8 bfr = w8[((tap * 4 + quad) * 128) + co];
                        #pragma unroll
                        for (int mt = 0; mt < 4; mt++)
                            acc[mt][nt] = __builtin_amdgcn_mfma_f32_16x16x32_bf16(
                                af[mt], bfr, acc[mt][nt], 0, 0, 0);
                    }
                }
            }
        }
    }

    // ---- epilogue: D row = quad*4+reg (pixel), col = n16 (co) ----
    #pragma unroll
    for (int mt = 0; mt < 4; mt++) {
        int pbase = wave_m * 64 + mt * 16 + quad * 4;   // 4 consecutive pixels
        int row = pbase >> 5, xc = pbase & 31;
        int gy = y0 + row;
        #pragma unroll
        for (int nt = 0; nt < 4; nt++) {
            int co = wave_n * 64 + nt * 16 + n16;
            size_t oi = ((size_t)bl * CH + co) * HW + gy * 32 + xc;
            float4v v = acc[mt][nt];
            float bb = bias[co];
            #pragma unroll
            for (int r = 0; r < 4; r++) {
                float val = v[r] + bb;
                if (RELU) val = fmaxf(val, 0.f);
                v[r] = val;
            }
            if (RES) {
                float4v rv = *reinterpret_cast<const float4v*>(&res[oi]);
                #pragma unroll
                for (int r = 0; r < 4; r++) v[r] += rv[r];
            }
            *reinterpret_cast<float4v*>(&out[oi]) = v;
        }
    }
}

// ---------------- attention logit conv: Ak = conv3x3(v + pos, aw_k) ----------------
__global__ __launch_bounds__(256) void k_attn(
    const float* __restrict__ v, const float* __restrict__ aw,
    float* __restrict__ ak)
{
    const int bl = blockIdx.x;
    const int h = blockIdx.y;
    const int y0 = blockIdx.z * 8;
    const int t = threadIdx.x;
    const int r = t >> 5, xx = t & 31;
    const int b = bl / 12, l = bl - b * 12;

    __shared__ float sx[2720];
    __shared__ float spos[32];

    if (t < 32) {
        int j2 = t & ~1;
        float freq = expf(-(float)j2 * 0.28782313662425576f);  // ln(10000)/32
        float ang = (float)l * freq;
        spos[t] = (t & 1) ? cosf(ang) : sinf(ang);
    }
    __syncthreads();

    const float* wb = aw + (h * 64 + 32) * 9;   // K-half of att_w

    float acc = 0.f;
    for (int ch = 0; ch < 4; ch++) {
        const int ci0 = ch * 8;
        for (int idx = t; idx < 2720; idx += 256) {
            int ci = idx / 340; int rem = idx - ci * 340;
            int row = rem / 34; int col = rem - row * 34;
            int gy = y0 - 1 + row, gx = col - 1;
            float val = 0.f;
            if (gy >= 0 && gy < 32 && gx >= 0 && gx < 32)
                val = v[(bl * CH + h * 32 + ci0 + ci) * HW + gy * 32 + gx] + spos[ci0 + ci];
            sx[idx] = val;
        }
        __syncthreads();
        #pragma unroll
        for (int ci = 0; ci < 8; ci++)
            #pragma unroll
            for (int ky = 0; ky < 3; ky++)
                #pragma unroll
                for (int kx = 0; kx < 3; kx++)
                    acc = fmaf(sx[ci * 340 + (r + ky) * 34 + xx + kx],
                               wb[(ci0 + ci) * 9 + ky * 3 + kx], acc);
        __syncthreads();
    }
    ak[((b * 4 + h) * 12 + l) * HW + (y0 + r) * 32 + xx] = acc;
}

// ---------------- softmax over 12 key frames (in-place) ----------------
__global__ void k_softmax(float* __restrict__ akw){
    int gid = blockIdx.x * blockDim.x + threadIdx.x;   // 8192
    if (gid >= 8192) return;
    int b = gid >> 12, rem = gid & 4095, h = rem >> 10, yx = rem & 1023;
    float* p = akw + ((b * 4 + h) * 12) * HW + yx;
    float a[12], m = -1e30f;
    #pragma unroll
    for (int l = 0; l < 12; l++) { a[l] = p[l * HW]; m = fmaxf(m, a[l]); }
    float s = 0.f;
    #pragma unroll
    for (int l = 0; l < 12; l++) { a[l] = expf(a[l] - m); s += a[l]; }
    float inv = 1.f / s;
    #pragma unroll
    for (int l = 0; l < 12; l++) p[l * HW] = a[l] * inv;
}

// ---------------- weighted sum over key frames + residual ----------------
__global__ void k_wsum(const float* __restrict__ akw, const float* __restrict__ v,
                       float* __restrict__ cur){
    int gid = blockIdx.x * blockDim.x + threadIdx.x;   // 262144
    int b = gid >> 17, rem = gid & 131071, c = rem >> 10, yx = rem & 1023;
    int h = c >> 5;
    const float* wp = akw + ((b * 4 + h) * 12) * HW + yx;
    const float* vp = v + (b * 12 * CH + c) * HW + yx;
    float s = 0.f;
    #pragma unroll
    for (int l = 0; l < 12; l++) s += wp[l * HW] * vp[l * CH * HW];
    float* cp = cur + (b * 12 * CH + c) * HW + yx;
    #pragma unroll
    for (int l = 0; l < 12; l++) cp[l * CH * HW] += s;
}

// ---------------- GroupNorm (groups=4) ----------------
__global__ __launch_bounds__(256) void k_gn(const float* __restrict__ xin,
    const float* __restrict__ gw, const float* __restrict__ gb,
    float* __restrict__ out)
{
    const int bl = blockIdx.x, g = blockIdx.y;
    const int t = threadIdx.x;
    const float* xp = xin + (bl * CH + g * 32) * HW;
    float s = 0.f, s2 = 0.f;
    for (int i = t; i < 32768; i += 256) { float val = xp[i]; s += val; s2 += val * val; }
    __shared__ float rs[256], rs2[256];
    rs[t] = s; rs2[t] = s2; __syncthreads();
    for (int ofs = 128; ofs > 0; ofs >>= 1) {
        if (t < ofs) { rs[t] += rs[t + ofs]; rs2[t] += rs2[t + ofs]; }
        __syncthreads();
    }
    const float mu = rs[0] * (1.f / 32768.f);
    const float var = rs2[0] * (1.f / 32768.f) - mu * mu;
    const float inv = rsqrtf(var + 1e-5f);
    const int obase = (bl * CH + g * 32) * HW;
    for (int i = t; i < 32768; i += 256) {
        int c = i >> 10; int gc = g * 32 + c;
        out[obase + i] = (xp[i] - mu) * inv * gw[gc] + gb[gc];
    }
}

extern "C" void kernel_launch(void* const* d_in, const int* in_sizes, int n_in,
                              void* d_out, int out_size, void* d_ws, size_t ws_size,
                              hipStream_t stream)
{
    const float* input = (const float*)d_in[0];
    // d_in[1] q_w, d_in[2] q_b, d_in[6] att_b provably cancel in key-axis softmax.
    const float* kv_w  = (const float*)d_in[3];
    const float* kv_b  = (const float*)d_in[4];
    const float* att_w = (const float*)d_in[5];
    const float* ff1_w = (const float*)d_in[7];
    const float* ff1_b = (const float*)d_in[8];
    const float* ff2_w = (const float*)d_in[9];
    const float* ff2_b = (const float*)d_in[10];
    const float* gn_w  = (const float*)d_in[11];
    const float* gn_b  = (const float*)d_in[12];

    float* ws  = (float*)d_ws;
    float* cur = ws;                         // (24,128,32,32) fp32
    float* v   = ws + (size_t)NELEM;
    float* akw = ws + (size_t)2 * NELEM;     // 98304 floats
    unsigned short* W2d  = (unsigned short*)(ws + (size_t)2 * NELEM + 98304);
    unsigned short* W2kv = W2d + 1474560;
    float* f1  = (float*)d_out;              // scratch; overwritten by final GN
    float* outp = (float*)d_out;

    // bf16 weight transforms (every launch; trivial cost)
    k_w2dense<<<5760, 256, 0, stream>>>(ff1_w, ff2_w, W2d);
    k_w2kv<<<720, 256, 0, stream>>>(kv_w, W2kv);

    hipMemcpyAsync(cur, input, (size_t)NELEM * sizeof(float),
                   hipMemcpyDeviceToDevice, stream);

    for (int li = 0; li < 5; li++) {
        // v = grouped conv(cur, kv_w) + kv_b
        k_conv_mfma<true, false, false><<<dim3(8, IMG), 256, 0, stream>>>(
            cur, W2kv + (size_t)li * 36864, kv_b + li * 128, nullptr, v);
        // attention logits from k = v + pos
        k_attn<<<dim3(IMG, 4, 4), 256, 0, stream>>>(v, att_w + (size_t)li * 2304, akw);
        k_softmax<<<32, 256, 0, stream>>>(akw);
        // cur += sum_l w*v (broadcast over query frames)
        k_wsum<<<1024, 256, 0, stream>>>(akw, v, cur);
        // f1 = relu(conv(cur, ff1)) ; v = conv(f1, ff2) + cur
        k_conv_mfma<false, true, false><<<dim3(8, IMG), 256, 0, stream>>>(
            cur, W2d + (size_t)(li * 2 + 0) * 147456, ff1_b + li * 128, nullptr, f1);
        k_conv_mfma<false, false, true><<<dim3(8, IMG), 256, 0, stream>>>(
            f1, W2d + (size_t)(li * 2 + 1) * 147456, ff2_b + li * 128, cur, v);
        k_gn<<<dim3(IMG, 4), 256, 0, stream>>>(
            v, gn_w + li * 128, gn_b + li * 128, (li == 4) ? outp : cur);
    }
}

// Round 4
// 846.829 us; speedup vs baseline: 4.0561x; 1.0142x over previous
//
#include <hip/hip_runtime.h>

// Problem: B=2, T=12, C=128, H=W=32, heads=4, dh=32, layers=5. All fp32 I/O.
// Algebra: softmax over the key axis cancels the q-conv and att_b entirely and
// makes attention weights query-independent (head output identical for all 12
// frames). Dense/grouped 3x3 convs -> implicit GEMM on bf16 MFMA.
#define NELEM 3145728   // 24*128*1024
#define IMG 24
#define CH 128
#define HW 1024

using short8  = __attribute__((ext_vector_type(8))) short;
using float4v = __attribute__((ext_vector_type(4))) float;

__device__ inline unsigned short f2bf(float f){
    union { float f; unsigned u; } c; c.f = f;
    return (unsigned short)((c.u + 0x7FFF + ((c.u >> 16) & 1)) >> 16);
}

// ---------------- weight transforms (fp32 -> bf16 MFMA-B layout) ----------------
// Dense: W2[li2][tap][cc][quad][co][j] = w[co][ci=cc*32+quad*8+j][tap], li2=li*2+s
__global__ void k_w2dense(const float* __restrict__ w1, const float* __restrict__ w2src,
                          unsigned short* __restrict__ dst){
    int idx = blockIdx.x * 256 + threadIdx.x;           // 10*147456
    if (idx >= 1474560) return;
    int li2 = idx / 147456, r1 = idx - li2 * 147456;
    int j = r1 & 7, t16 = r1 >> 3;
    int co = t16 & 127, tcq = t16 >> 7;
    int quad = tcq & 3, cc = (tcq >> 2) & 3, tap = tcq >> 4;
    const float* base = ((li2 & 1) ? w2src : w1) + (size_t)(li2 >> 1) * 147456;
    dst[idx] = f2bf(base[(co * 128 + cc * 32 + quad * 8 + j) * 9 + tap]);
}
// Grouped kv: W2[li][tap][quad][co(=h*32+col)][j] = kv_w[li][h][col][ci=quad*8+j][tap]
__global__ void k_w2kv(const float* __restrict__ w, unsigned short* __restrict__ dst){
    int idx = blockIdx.x * 256 + threadIdx.x;           // 5*36864
    if (idx >= 184320) return;
    int li = idx / 36864, r1 = idx - li * 36864;
    int j = r1 & 7, t16 = r1 >> 3;
    int co = t16 & 127, tq = t16 >> 7;
    int quad = tq & 3, tap = tq >> 2;
    int h = co >> 5, col = co & 31;
    dst[idx] = f2bf(w[(size_t)(((li * 4 + h) * 32 + col) * 32 + quad * 8 + j) * 9 + tap]);
}

// ---------------- implicit-GEMM 3x3 conv via bf16 MFMA ----------------
// Block: 128 px (4 image rows) x 64 co; grid (8, IMG, 2). 4 waves, each one
// 32-px M-strip x all 64 co (2x4 frags). All waves read the SAME B fragments
// (L1 reuse); B prefetched one K-step ahead. A in LDS: [oct][pos(205)][8ci].
// GROUPED (kv): co-half zc covers heads 2zc,2zc+1 -> stage only those 8 octets.
template<bool GROUPED, bool RELU, bool RES>
__global__ __launch_bounds__(256) void k_conv_mfma(
    const float* __restrict__ x, const unsigned short* __restrict__ w2,
    const float* __restrict__ bias, const float* __restrict__ res,
    float* __restrict__ out)
{
    const int rq = blockIdx.x;       // y0 = rq*4
    const int bl = blockIdx.y;       // 0..23
    const int zc = blockIdx.z;       // co half
    const int y0 = rq * 4;
    const int t = threadIdx.x;
    const int wave = t >> 6, lane = t & 63;
    const int n16 = lane & 15, quad = lane >> 4;
    const int co_base = zc * 64;

    constexpr int NOCT = GROUPED ? 8 : 16;
    __shared__ short8 sA[NOCT * 205];
    const int oct0 = GROUPED ? zc * 8 : 0;

    // stage A: 6 rows x 34 cols x NOCT ci-octets (zero-padded borders)
    for (int idx = t; idx < NOCT * 204; idx += 256) {
        int oct = idx / 204, pos = idx - oct * 204;
        int row = pos / 34, col = pos - row * 34;
        int gy = y0 - 1 + row, gx = col - 1;
        bool ok = (gy >= 0 && gy < 32 && gx >= 0 && gx < 32);
        const float* gp = x + ((size_t)bl * CH + (oct0 + oct) * 8) * HW + gy * 32 + gx;
        short8 v;
        #pragma unroll
        for (int j = 0; j < 8; j++)
            v[j] = ok ? (short)f2bf(gp[j * HW]) : (short)0;
        sA[oct * 205 + pos] = v;
    }
    __syncthreads();

    float4v acc[2][4];
    #pragma unroll
    for (int a = 0; a < 2; a++)
        #pragma unroll
        for (int b = 0; b < 4; b++) acc[a][b] = (float4v){0.f, 0.f, 0.f, 0.f};

    const short8* w8 = reinterpret_cast<const short8*>(w2);
    const int pcol = n16;  // lane's M index within a 16-tile

    if (!GROUPED) {
        short8 bcur[4];
        #pragma unroll
        for (int nt = 0; nt < 4; nt++)
            bcur[nt] = w8[quad * 128 + co_base + nt * 16 + n16];   // k=0
        #pragma unroll
        for (int k = 0; k < 36; k++) {
            const int tap = k >> 2, cc = k & 3;
            const int ky = tap / 3, kx = tap - ky * 3;
            short8 bnxt[4];
            if (k < 35) {
                const int kn = k + 1, tapn = kn >> 2, ccn = kn & 3;
                #pragma unroll
                for (int nt = 0; nt < 4; nt++)
                    bnxt[nt] = w8[((tapn * 4 + ccn) * 4 + quad) * 128 + co_base + nt * 16 + n16];
            }
            short8 af[2];
            #pragma unroll
            for (int mt = 0; mt < 2; mt++) {
                int p = wave * 32 + mt * 16;          // strip base
                int row = p >> 5, xh = p & 31;
                int pos = (row + ky) * 34 + xh + pcol + kx;
                af[mt] = sA[(cc * 4 + quad) * 205 + pos];
            }
            #pragma unroll
            for (int mt = 0; mt < 2; mt++)
                #pragma unroll
                for (int nt = 0; nt < 4; nt++)
                    acc[mt][nt] = __builtin_amdgcn_mfma_f32_16x16x32_bf16(
                        af[mt], bcur[nt], acc[mt][nt], 0, 0, 0);
            if (k < 35) {
                #pragma unroll
                for (int nt = 0; nt < 4; nt++) bcur[nt] = bnxt[nt];
            }
        }
    } else {
        #pragma unroll
        for (int tap = 0; tap < 9; tap++) {
            const int ky = tap / 3, kx = tap - ky * 3;
            #pragma unroll
            for (int hl = 0; hl < 2; hl++) {       // local head
                short8 af[2];
                #pragma unroll
                for (int mt = 0; mt < 2; mt++) {
                    int p = wave * 32 + mt * 16;
                    int row = p >> 5, xh = p & 31;
                    int pos = (row + ky) * 34 + xh + pcol + kx;
                    af[mt] = sA[(hl * 4 + quad) * 205 + pos];
                }
                #pragma unroll
                for (int n2 = 0; n2 < 2; n2++) {
                    int nt = hl * 2 + n2;
                    short8 b = w8[(tap * 4 + quad) * 128 + co_base + nt * 16 + n16];
                    #pragma unroll
                    for (int mt = 0; mt < 2; mt++)
                        acc[mt][nt] = __builtin_amdgcn_mfma_f32_16x16x32_bf16(
                            af[mt], b, acc[mt][nt], 0, 0, 0);
                }
            }
        }
    }

    // epilogue: D row(pixel) = quad*4+reg, col(co) = n16
    #pragma unroll
    for (int mt = 0; mt < 2; mt++) {
        int pbase = wave * 32 + mt * 16 + quad * 4;   // 4 consecutive pixels
        int row = pbase >> 5, xc = pbase & 31;
        int gy = y0 + row;
        #pragma unroll
        for (int nt = 0; nt < 4; nt++) {
            int co = co_base + nt * 16 + n16;
            size_t oi = ((size_t)bl * CH + co) * HW + gy * 32 + xc;
            float4v v = acc[mt][nt];
            float bb = bias[co];
            #pragma unroll
            for (int r = 0; r < 4; r++) {
                float val = v[r] + bb;
                if (RELU) val = fmaxf(val, 0.f);
                v[r] = val;
            }
            if (RES) {
                float4v rv = *reinterpret_cast<const float4v*>(&res[oi]);
                #pragma unroll
                for (int r = 0; r < 4; r++) v[r] += rv[r];
            }
            *reinterpret_cast<float4v*>(&out[oi]) = v;
        }
    }
}

// ---------------- attention logit conv: Ak = conv3x3(v + pos, aw_k) ----------------
__global__ __launch_bounds__(256) void k_attn(
    const float* __restrict__ v, const float* __restrict__ aw,
    float* __restrict__ ak)
{
    const int bl = blockIdx.x;
    const int h = blockIdx.y;
    const int y0 = blockIdx.z * 8;
    const int t = threadIdx.x;
    const int r = t >> 5, xx = t & 31;
    const int b = bl / 12, l = bl - b * 12;

    __shared__ float sx[2720];
    __shared__ float spos[32];

    if (t < 32) {
        int j2 = t & ~1;
        float freq = expf(-(float)j2 * 0.28782313662425576f);  // ln(10000)/32
        float ang = (float)l * freq;
        spos[t] = (t & 1) ? cosf(ang) : sinf(ang);
    }
    __syncthreads();

    const float* wb = aw + (h * 64 + 32) * 9;   // K-half of att_w

    float acc = 0.f;
    for (int ch = 0; ch < 4; ch++) {
        const int ci0 = ch * 8;
        for (int idx = t; idx < 2720; idx += 256) {
            int ci = idx / 340; int rem = idx - ci * 340;
            int row = rem / 34; int col = rem - row * 34;
            int gy = y0 - 1 + row, gx = col - 1;
            float val = 0.f;
            if (gy >= 0 && gy < 32 && gx >= 0 && gx < 32)
                val = v[(bl * CH + h * 32 + ci0 + ci) * HW + gy * 32 + gx] + spos[ci0 + ci];
            sx[idx] = val;
        }
        __syncthreads();
        #pragma unroll
        for (int ci = 0; ci < 8; ci++)
            #pragma unroll
            for (int ky = 0; ky < 3; ky++)
                #pragma unroll
                for (int kx = 0; kx < 3; kx++)
                    acc = fmaf(sx[ci * 340 + (r + ky) * 34 + xx + kx],
                               wb[(ci0 + ci) * 9 + ky * 3 + kx], acc);
        __syncthreads();
    }
    ak[((b * 4 + h) * 12 + l) * HW + (y0 + r) * 32 + xx] = acc;
}

// ---------------- fused softmax + weighted sum + residual ----------------
__global__ void k_wsum(const float* __restrict__ ak, const float* __restrict__ v,
                       float* __restrict__ cur){
    int gid = blockIdx.x * 256 + threadIdx.x;   // 262144 = B*128*1024
    int b = gid >> 17, rem = gid & 131071, c = rem >> 10, yx = rem & 1023;
    int h = c >> 5;
    const float* wp = ak + ((b * 4 + h) * 12) * HW + yx;
    float a[12], m = -1e30f;
    #pragma unroll
    for (int l = 0; l < 12; l++) { a[l] = wp[l * HW]; m = fmaxf(m, a[l]); }
    float ssum = 0.f;
    #pragma unroll
    for (int l = 0; l < 12; l++) { a[l] = __expf(a[l] - m); ssum += a[l]; }
    float invs = 1.f / ssum;
    const float* vp = v + (b * 12 * CH + c) * HW + yx;
    float s = 0.f;
    #pragma unroll
    for (int l = 0; l < 12; l++) s += a[l] * vp[l * CH * HW];
    s *= invs;
    float* cp = cur + (b * 12 * CH + c) * HW + yx;
    #pragma unroll
    for (int l = 0; l < 12; l++) cp[l * CH * HW] += s;
}

// ---------------- GroupNorm: partial stats -> finalize -> apply ----------------
__global__ __launch_bounds__(256) void k_gnstat(const float* __restrict__ x,
                                                float* __restrict__ pstat){
    const int bg = blockIdx.x, s = blockIdx.y;   // bg = bl*4+g (96), s = 0..7
    const int t = threadIdx.x;
    const float4v* xp = (const float4v*)(x + (size_t)bg * 32768 + s * 4096);
    float sum = 0.f, sq = 0.f;
    #pragma unroll
    for (int i = 0; i < 4; i++) {
        float4v v = xp[t + i * 256];
        #pragma unroll
        for (int r = 0; r < 4; r++) { sum += v[r]; sq += v[r] * v[r]; }
    }
    #pragma unroll
    for (int o = 32; o > 0; o >>= 1) {
        sum += __shfl_down(sum, o); sq += __shfl_down(sq, o);
    }
    __shared__ float ls[8];
    int wv = t >> 6, ln = t & 63;
    if (ln == 0) { ls[wv] = sum; ls[4 + wv] = sq; }
    __syncthreads();
    if (t == 0) {
        pstat[(bg * 8 + s) * 2]     = ls[0] + ls[1] + ls[2] + ls[3];
        pstat[(bg * 8 + s) * 2 + 1] = ls[4] + ls[5] + ls[6] + ls[7];
    }
}

__global__ void k_gnfin(const float* __restrict__ pstat, float* __restrict__ minv){
    int t = threadIdx.x;
    if (t >= 96) return;
    float S = 0.f, Q = 0.f;
    #pragma unroll
    for (int s = 0; s < 8; s++) { S += pstat[(t * 8 + s) * 2]; Q += pstat[(t * 8 + s) * 2 + 1]; }
    float mu = S * (1.f / 32768.f);
    float var = Q * (1.f / 32768.f) - mu * mu;
    minv[t * 2] = mu; minv[t * 2 + 1] = rsqrtf(var + 1e-5f);
}

__global__ __launch_bounds__(256) void k_gnapply(const float* __restrict__ x,
    const float* __restrict__ minv, const float* __restrict__ gw,
    const float* __restrict__ gb, float* __restrict__ out){
    size_t i4 = ((size_t)blockIdx.x * 256 + threadIdx.x) * 4;
    int c  = (int)((i4 >> 10) & 127);     // channel within image (uniform per block)
    int bg = (int)(i4 >> 15);             // bl*4 + g
    float mu = minv[bg * 2], inv = minv[bg * 2 + 1];
    float g_ = gw[c], b_ = gb[c];
    float4v v = *(const float4v*)(x + i4);
    #pragma unroll
    for (int r = 0; r < 4; r++) v[r] = (v[r] - mu) * inv * g_ + b_;
    *(float4v*)(out + i4) = v;
}

extern "C" void kernel_launch(void* const* d_in, const int* in_sizes, int n_in,
                              void* d_out, int out_size, void* d_ws, size_t ws_size,
                              hipStream_t stream)
{
    const float* input = (const float*)d_in[0];
    // d_in[1] q_w, d_in[2] q_b, d_in[6] att_b provably cancel in key-axis softmax.
    const float* kv_w  = (const float*)d_in[3];
    const float* kv_b  = (const float*)d_in[4];
    const float* att_w = (const float*)d_in[5];
    const float* ff1_w = (const float*)d_in[7];
    const float* ff1_b = (const float*)d_in[8];
    const float* ff2_w = (const float*)d_in[9];
    const float* ff2_b = (const float*)d_in[10];
    const float* gn_w  = (const float*)d_in[11];
    const float* gn_b  = (const float*)d_in[12];

    float* ws  = (float*)d_ws;
    float* cur = ws;                         // (24,128,32,32) fp32
    float* v   = ws + (size_t)NELEM;
    float* akw = ws + (size_t)2 * NELEM;     // 98304 floats (attn logits)
    float* pstat = akw + 98304;              // 1536
    float* minv  = pstat + 1536;             // 192
    unsigned short* W2d  = (unsigned short*)(minv + 192);
    unsigned short* W2kv = W2d + 1474560;
    float* f1  = (float*)d_out;              // scratch; overwritten by final GN
    float* outp = (float*)d_out;

    k_w2dense<<<5760, 256, 0, stream>>>(ff1_w, ff2_w, W2d);
    k_w2kv<<<720, 256, 0, stream>>>(kv_w, W2kv);

    hipMemcpyAsync(cur, input, (size_t)NELEM * sizeof(float),
                   hipMemcpyDeviceToDevice, stream);

    for (int li = 0; li < 5; li++) {
        // v = grouped conv(cur, kv_w) + kv_b
        k_conv_mfma<true, false, false><<<dim3(8, IMG, 2), 256, 0, stream>>>(
            cur, W2kv + (size_t)li * 36864, kv_b + li * 128, nullptr, v);
        // attention logits from k = v + pos
        k_attn<<<dim3(IMG, 4, 4), 256, 0, stream>>>(v, att_w + (size_t)li * 2304, akw);
        // cur += attention output (softmax fused, broadcast over query frames)
        k_wsum<<<1024, 256, 0, stream>>>(akw, v, cur);
        // f1 = relu(conv(cur, ff1)) ; v = conv(f1, ff2) + cur
        k_conv_mfma<false, true, false><<<dim3(8, IMG, 2), 256, 0, stream>>>(
            cur, W2d + (size_t)(li * 2 + 0) * 147456, ff1_b + li * 128, nullptr, f1);
        k_conv_mfma<false, false, true><<<dim3(8, IMG, 2), 256, 0, stream>>>(
            f1, W2d + (size_t)(li * 2 + 1) * 147456, ff2_b + li * 128, cur, v);
        // group norm
        k_gnstat<<<dim3(96, 8), 256, 0, stream>>>(v, pstat);
        k_gnfin<<<1, 128, 0, stream>>>(pstat, minv);
        k_gnapply<<<3072, 256, 0, stream>>>(v, minv, gn_w + li * 128, gn_b + li * 128,
                                            (li == 4) ? outp : cur);
    }
}

// Round 6
// 659.194 us; speedup vs baseline: 5.2106x; 1.2846x over previous
//
#include <hip/hip_runtime.h>

// B=2, T=12, C=128, H=W=32, heads=4, dh=32, layers=5. fp32 I/O.
// Algebra: key-axis softmax cancels q-conv & att_b; attention weights are
// query-independent (head output broadcast over the 12 frames).
// Layout: channels-last fp32 activations [img][1024px][128c] + padded bf16
// copies A2[img][34*34 pos][128c] so conv MFMA A-fragments are direct
// contiguous global loads (no LDS in the convs).
// Buffer plan (fixes round-5 aliasing NaN): v fp32 lives in d_out (dead before
// the final output write); A2a/A2v live in ws; ff2 + GN apply are in-place on
// cur (element-wise safe).
#define NELEM 3145728
#define IMG 24
#define CH 128
#define HW 1024
#define PADP 1156          // 34*34
#define A2IMG 147968       // 1156*128

using short8  = __attribute__((ext_vector_type(8))) short;
using float4v = __attribute__((ext_vector_type(4))) float;

__device__ inline unsigned short f2bf(float f){
    union { float f; unsigned u; } c; c.f = f;
    return (unsigned short)((c.u + 0x7FFF + ((c.u >> 16) & 1)) >> 16);
}
__device__ inline float bf2f(unsigned short h){
    union { unsigned u; float f; } c; c.u = ((unsigned)h) << 16; return c.f;
}

// ---------------- weight transforms (fp32 -> bf16 MFMA-B layout) ----------------
__global__ void k_w2dense(const float* __restrict__ w1, const float* __restrict__ w2src,
                          unsigned short* __restrict__ dst){
    int idx = blockIdx.x * 256 + threadIdx.x;           // 10*147456
    if (idx >= 1474560) return;
    int li2 = idx / 147456, r1 = idx - li2 * 147456;
    int j = r1 & 7, t16 = r1 >> 3;
    int co = t16 & 127, tcq = t16 >> 7;
    int quad = tcq & 3, cc = (tcq >> 2) & 3, tap = tcq >> 4;
    const float* base = ((li2 & 1) ? w2src : w1) + (size_t)(li2 >> 1) * 147456;
    dst[idx] = f2bf(base[(co * 128 + cc * 32 + quad * 8 + j) * 9 + tap]);
}
__global__ void k_w2kv(const float* __restrict__ w, unsigned short* __restrict__ dst){
    int idx = blockIdx.x * 256 + threadIdx.x;           // 5*36864
    if (idx >= 184320) return;
    int li = idx / 36864, r1 = idx - li * 36864;
    int j = r1 & 7, t16 = r1 >> 3;
    int co = t16 & 127, tq = t16 >> 7;
    int quad = tq & 3, tap = tq >> 2;
    int h = co >> 5, col = co & 31;
    dst[idx] = f2bf(w[(size_t)(((li * 4 + h) * 32 + col) * 32 + quad * 8 + j) * 9 + tap]);
}

// ---------------- zero the padded borders of the A2 buffers ----------------
__global__ void k_border(unsigned short* __restrict__ a, unsigned short* __restrict__ b){
    int gid = blockIdx.x * 256 + threadIdx.x;   // 2*24*132*128 = 811008
    if (gid >= 811008) return;
    int c = gid & 127, r = gid >> 7;
    int bp = r % 132, r2 = r / 132;
    int img = r2 % 24, buf = r2 / 24;
    int pos;
    if (bp < 34) pos = bp;
    else if (bp < 68) pos = 33 * 34 + (bp - 34);
    else if (bp < 100) pos = (bp - 68 + 1) * 34;
    else pos = (bp - 100 + 1) * 34 + 33;
    unsigned short* p = buf ? b : a;
    p[(size_t)img * A2IMG + pos * 128 + c] = 0;
}

// ---------------- init: NCHW fp32 input -> CL cur fp32 + A2a bf16 ----------------
__global__ __launch_bounds__(256) void k_init(const float* __restrict__ in,
    float* __restrict__ cur, unsigned short* __restrict__ a2){
    int gid = blockIdx.x * 256 + threadIdx.x;   // 24*1024*32
    int c4 = (gid & 31) * 4, px = (gid >> 5) & 1023, img = gid >> 15;
    float4v v;
    #pragma unroll
    for (int j = 0; j < 4; j++)
        v[j] = in[((size_t)img * 128 + c4 + j) * HW + px];
    *(float4v*)(cur + ((size_t)img * HW + px) * 128 + c4) = v;
    int pos = ((px >> 5) + 1) * 34 + (px & 31) + 1;
    unsigned short* ap = a2 + ((size_t)img * PADP + pos) * 128 + c4;
    #pragma unroll
    for (int j = 0; j < 4; j++) ap[j] = f2bf(v[j]);
}

// ---------------- implicit-GEMM 3x3 conv, channels-last, no LDS ----------------
// grid (8 rq, 24 img, 2 zc). Block 256 = 4 waves, wave grid 2m x 2n.
// Block tile 128px(4 rows) x 64co. Wave: 4 m-frags(16px) x 2 n-frags(16co).
// A: direct global short8 loads from padded A2 (tap shift = address offset).
// B: global short8 from frag-native W2. Both rotated through 3 prefetch slots.
template<bool GROUPED, bool RELU, bool RES, bool EF32, bool EA2, bool STAT>
__global__ __launch_bounds__(256) void k_conv(
    const unsigned short* __restrict__ a2in, const unsigned short* __restrict__ w2,
    const float* __restrict__ bias, const float* __restrict__ res,
    float* __restrict__ outf, unsigned short* __restrict__ outa2,
    float* __restrict__ pstat)
{
    const int y0 = blockIdx.x * 4;
    const int img = blockIdx.y;
    const int zc = blockIdx.z;
    const int t = threadIdx.x;
    const int wave = t >> 6, lane = t & 63;
    const int wm = wave & 1, wn = wave >> 1;
    const int n16 = lane & 15, quad = lane >> 4;
    const int cog = zc * 64 + wn * 32;          // wave's co base
    const int head = zc * 2 + wn;               // co group (grouped head / GN group)

    const short8* w8 = reinterpret_cast<const short8*>(w2);
    const unsigned short* abase = a2in + (size_t)img * A2IMG;

    constexpr int NK = GROUPED ? 9 : 36;

    float4v acc[4][2];
    #pragma unroll
    for (int a = 0; a < 4; a++)
        #pragma unroll
        for (int b = 0; b < 2; b++) acc[a][b] = (float4v){0.f,0.f,0.f,0.f};

    short8 af[3][4], bf[3][2];

    auto loadA = [&](int k, int s){
        const int tap = GROUPED ? k : (k >> 2);
        const int cc  = GROUPED ? 0 : (k & 3);
        const int ky = tap / 3, kx = tap - ky * 3;
        const int ci = (GROUPED ? head * 32 : cc * 32) + quad * 8;
        #pragma unroll
        for (int mt = 0; mt < 4; mt++) {
            int y = y0 + wm * 2 + (mt >> 1);
            int pos = (y + ky) * 34 + (mt & 1) * 16 + kx + n16;
            af[s][mt] = *reinterpret_cast<const short8*>(abase + (size_t)pos * 128 + ci);
        }
    };
    auto loadB = [&](int k, int s){
        #pragma unroll
        for (int nt = 0; nt < 2; nt++)
            bf[s][nt] = w8[(k * 4 + quad) * 128 + cog + nt * 16 + n16];
    };

    #pragma unroll
    for (int k = 0; k < 3; k++) { loadA(k, k); loadB(k, k); }
    #pragma unroll
    for (int k = 0; k < NK; k++) {
        const int s = k % 3;
        #pragma unroll
        for (int mt = 0; mt < 4; mt++)
            #pragma unroll
            for (int nt = 0; nt < 2; nt++)
                acc[mt][nt] = __builtin_amdgcn_mfma_f32_16x16x32_bf16(
                    af[s][mt], bf[s][nt], acc[mt][nt], 0, 0, 0);
        if (k + 3 < NK) { loadA(k + 3, s); loadB(k + 3, s); }
    }

    // epilogue: D col = n16 (co offset), row = quad*4+reg (x offset)
    float s1 = 0.f, s2 = 0.f;
    #pragma unroll
    for (int mt = 0; mt < 4; mt++) {
        int y = y0 + wm * 2 + (mt >> 1);
        int xb = (mt & 1) * 16 + quad * 4;
        #pragma unroll
        for (int nt = 0; nt < 2; nt++) {
            int co = cog + nt * 16 + n16;
            float bb = bias[co];
            #pragma unroll
            for (int r = 0; r < 4; r++) {
                int px = y * 32 + xb + r;
                float val = acc[mt][nt][r] + bb;
                if (RELU) val = fmaxf(val, 0.f);
                size_t ci = ((size_t)img * HW + px) * 128 + co;
                if (RES) val += res[ci];
                if (EF32) outf[ci] = val;
                if (EA2) {
                    int pos = (y + 1) * 34 + xb + r + 1;
                    outa2[((size_t)img * PADP + pos) * 128 + co] = f2bf(val);
                }
                if (STAT) { s1 += val; s2 += val * val; }
            }
        }
    }
    if (STAT) {
        #pragma unroll
        for (int o = 32; o > 0; o >>= 1) {
            s1 += __shfl_down(s1, o); s2 += __shfl_down(s2, o);
        }
        if (lane == 0) {
            atomicAdd(&pstat[(img * 4 + head) * 2], s1);
            atomicAdd(&pstat[(img * 4 + head) * 2 + 1], s2);
        }
    }
}

// ---------------- attention logit conv (reads padded bf16 A2v) ----------------
__global__ __launch_bounds__(256) void k_attn(
    const unsigned short* __restrict__ a2v, const float* __restrict__ aw,
    float* __restrict__ ak, float* __restrict__ pstat)
{
    const int img = blockIdx.x;            // b*12 + l
    const int h = blockIdx.y;
    const int y0 = blockIdx.z * 8;
    const int t = threadIdx.x;
    const int b = img / 12, l = img - b * 12;

    if (blockIdx.x == 0 && blockIdx.y == 0 && blockIdx.z == 0 && t < 192)
        pstat[t] = 0.f;                     // zero GN stats for this layer's ff2

    __shared__ float sxv[32 * 341];         // ci-major, pos stride 341
    __shared__ float spos[32];
    if (t < 32) {
        int j2 = t & ~1;
        float freq = __expf(-(float)j2 * 0.28782313662425576f);
        float ang = (float)l * freq;
        spos[t] = (t & 1) ? __cosf(ang) : __sinf(ang);
    }
    __syncthreads();

    // stage 10 padded rows x 34 cols x 32 ci, add pos on interior
    const unsigned short* vb = a2v + (size_t)img * A2IMG + h * 32;
    for (int idx = t; idx < 1360; idx += 256) {
        int q = idx & 3, pos = idx >> 2;
        int ppos = y0 * 34 + pos;
        int row = y0 + pos / 34, col = pos - (pos / 34) * 34;
        bool inter = (row >= 1 && row <= 32 && col >= 1 && col <= 32);
        short8 vv = *reinterpret_cast<const short8*>(vb + (size_t)ppos * 128 + q * 8);
        #pragma unroll
        for (int j = 0; j < 8; j++) {
            float f = bf2f((unsigned short)vv[j]);
            if (inter) f += spos[q * 8 + j];
            sxv[(q * 8 + j) * 341 + pos] = f;
        }
    }
    __syncthreads();

    const float* wb = aw + (h * 64 + 32) * 9;   // K-half weights (uniform -> s_load)
    const int r = t >> 5, xx = t & 31;
    float acc = 0.f;
    #pragma unroll 4
    for (int ci = 0; ci < 32; ci++) {
        #pragma unroll
        for (int ky = 0; ky < 3; ky++)
            #pragma unroll
            for (int kx = 0; kx < 3; kx++)
                acc = fmaf(sxv[ci * 341 + (r + ky) * 34 + xx + kx],
                           wb[ci * 9 + ky * 3 + kx], acc);
    }
    ak[((b * 4 + h) * 12 + l) * HW + (y0 + r) * 32 + xx] = acc;
}

// ---------------- fused softmax + weighted sum + residual (+A2a emit) ----------------
__global__ __launch_bounds__(256) void k_wsum(const float* __restrict__ ak,
    const float* __restrict__ v, float* __restrict__ cur,
    unsigned short* __restrict__ a2a)
{
    int gid = blockIdx.x * 256 + threadIdx.x;   // 2*1024*32
    int c4 = (gid & 31) * 4, px = (gid >> 5) & 1023, b = gid >> 15;
    int h = c4 >> 5;
    const float* wp = ak + ((b * 4 + h) * 12) * HW + px;
    float a[12], m = -1e30f;
    #pragma unroll
    for (int l = 0; l < 12; l++) { a[l] = wp[l * HW]; m = fmaxf(m, a[l]); }
    float ssum = 0.f;
    #pragma unroll
    for (int l = 0; l < 12; l++) { a[l] = __expf(a[l] - m); ssum += a[l]; }
    float invs = 1.f / ssum;
    float4v s = (float4v){0.f,0.f,0.f,0.f};
    #pragma unroll
    for (int l = 0; l < 12; l++) {
        float4v vv = *(const float4v*)(v + (((size_t)(b * 12 + l) * HW) + px) * 128 + c4);
        #pragma unroll
        for (int j = 0; j < 4; j++) s[j] += a[l] * vv[j];
    }
    #pragma unroll
    for (int j = 0; j < 4; j++) s[j] *= invs;
    int pos = ((px >> 5) + 1) * 34 + (px & 31) + 1;
    #pragma unroll
    for (int l = 0; l < 12; l++) {
        size_t ci = (((size_t)(b * 12 + l) * HW) + px) * 128 + c4;
        float4v cv = *(float4v*)(cur + ci);
        #pragma unroll
        for (int j = 0; j < 4; j++) cv[j] += s[j];
        *(float4v*)(cur + ci) = cv;
        unsigned short* ap = a2a + ((size_t)(b * 12 + l) * PADP + pos) * 128 + c4;
        #pragma unroll
        for (int j = 0; j < 4; j++) ap[j] = f2bf(cv[j]);
    }
}

// ---------------- GroupNorm finalize+apply (in-place on cur / final NCHW) ----------------
template<bool LAST>
__global__ __launch_bounds__(256) void k_gnapply(const float* __restrict__ y,
    const float* __restrict__ pstat, const float* __restrict__ gw,
    const float* __restrict__ gb, float* __restrict__ cur,
    unsigned short* __restrict__ a2a, float* __restrict__ outp)
{
    int gid = blockIdx.x * 256 + threadIdx.x;   // 24*1024*32
    if (!LAST) {
        int c4 = (gid & 31) * 4, px = (gid >> 5) & 1023, img = gid >> 15;
        int g = c4 >> 5;
        float S = pstat[(img * 4 + g) * 2], Q = pstat[(img * 4 + g) * 2 + 1];
        float mu = S * (1.f / 32768.f);
        float inv = rsqrtf(Q * (1.f / 32768.f) - mu * mu + 1e-5f);
        float4v vv = *(const float4v*)(y + ((size_t)img * HW + px) * 128 + c4);
        int pos = ((px >> 5) + 1) * 34 + (px & 31) + 1;
        size_t ci = ((size_t)img * HW + px) * 128 + c4;
        unsigned short* ap = a2a + ((size_t)img * PADP + pos) * 128 + c4;
        #pragma unroll
        for (int j = 0; j < 4; j++) {
            float val = (vv[j] - mu) * inv * gw[c4 + j] + gb[c4 + j];
            vv[j] = val;
            ap[j] = f2bf(val);
        }
        *(float4v*)(cur + ci) = vv;
    } else {
        int px4 = (gid & 255) * 4, c = (gid >> 8) & 127, img = gid >> 15;
        int g = c >> 5;
        float S = pstat[(img * 4 + g) * 2], Q = pstat[(img * 4 + g) * 2 + 1];
        float mu = S * (1.f / 32768.f);
        float inv = rsqrtf(Q * (1.f / 32768.f) - mu * mu + 1e-5f);
        float gg = gw[c], bb = gb[c];
        float4v o;
        #pragma unroll
        for (int j = 0; j < 4; j++) {
            float val = y[((size_t)img * HW + px4 + j) * 128 + c];
            o[j] = (val - mu) * inv * gg + bb;
        }
        *(float4v*)(outp + ((size_t)img * 128 + c) * HW + px4) = o;
    }
}

extern "C" void kernel_launch(void* const* d_in, const int* in_sizes, int n_in,
                              void* d_out, int out_size, void* d_ws, size_t ws_size,
                              hipStream_t stream)
{
    const float* input = (const float*)d_in[0];
    // d_in[1] q_w, d_in[2] q_b, d_in[6] att_b cancel in key-axis softmax.
    const float* kv_w  = (const float*)d_in[3];
    const float* kv_b  = (const float*)d_in[4];
    const float* att_w = (const float*)d_in[5];
    const float* ff1_w = (const float*)d_in[7];
    const float* ff1_b = (const float*)d_in[8];
    const float* ff2_w = (const float*)d_in[9];
    const float* ff2_b = (const float*)d_in[10];
    const float* gn_w  = (const float*)d_in[11];
    const float* gn_b  = (const float*)d_in[12];

    // ws layout (~30.5 MB): no buffer aliases another live buffer.
    float* ws  = (float*)d_ws;
    float* cur = ws;                          // CL fp32 (24,1024,128)
    float* ak  = ws + (size_t)NELEM;          // 98304
    float* pstat = ak + 98304;                // 192
    unsigned short* W2d  = (unsigned short*)(pstat + 192);   // 1,474,560
    unsigned short* W2kv = W2d + 1474560;                    // 184,320
    unsigned short* A2v  = W2kv + 184320;                    // 24*147968
    unsigned short* A2a  = A2v + (size_t)IMG * A2IMG;        // 24*147968
    // d_out doubles as the fp32 v buffer (dead before the final output write).
    float* v    = (float*)d_out;
    float* outp = (float*)d_out;

    k_w2dense<<<5760, 256, 0, stream>>>(ff1_w, ff2_w, W2d);
    k_w2kv<<<720, 256, 0, stream>>>(kv_w, W2kv);
    k_border<<<3168, 256, 0, stream>>>(A2a, A2v);
    k_init<<<3072, 256, 0, stream>>>(input, cur, A2a);

    for (int li = 0; li < 5; li++) {
        // v (d_out) = grouped conv(A2a) + kv_b ; also emit A2v bf16
        k_conv<true, false, false, true, true, false><<<dim3(8, IMG, 2), 256, 0, stream>>>(
            A2a, W2kv + (size_t)li * 36864, kv_b + li * 128, nullptr, v, A2v, nullptr);
        // attention logits from k = v + pos (also zeroes pstat for this layer)
        k_attn<<<dim3(IMG, 4, 4), 256, 0, stream>>>(A2v, att_w + (size_t)li * 2304, ak, pstat);
        // cur += softmax-weighted sum of v (broadcast over frames); emit A2a
        k_wsum<<<256, 256, 0, stream>>>(ak, v, cur, A2a);
        // f1 = relu(conv(A2a, ff1)) -> A2v only
        k_conv<false, true, false, false, true, false><<<dim3(8, IMG, 2), 256, 0, stream>>>(
            A2a, W2d + (size_t)(li * 2 + 0) * 147456, ff1_b + li * 128, nullptr, nullptr, A2v, nullptr);
        // cur = conv(A2v, ff2) + cur  (in-place, element-wise) + GN partial stats
        k_conv<false, false, true, true, false, true><<<dim3(8, IMG, 2), 256, 0, stream>>>(
            A2v, W2d + (size_t)(li * 2 + 1) * 147456, ff2_b + li * 128, cur, cur, nullptr, pstat);
        // GN apply: in-place on cur + A2a emit, or final NCHW transpose to d_out
        if (li == 4)
            k_gnapply<true><<<3072, 256, 0, stream>>>(cur, pstat, gn_w + li * 128,
                gn_b + li * 128, nullptr, nullptr, outp);
        else
            k_gnapply<false><<<3072, 256, 0, stream>>>(cur, pstat, gn_w + li * 128,
                gn_b + li * 128, cur, A2a, nullptr);
    }
}